// Round 7
// baseline (4487.868 us; speedup 1.0000x reference)
//
#include <hip/hip_runtime.h>
#include <hip/hip_bf16.h>

#define C_   256
#define P_   1024
#define N_   32768
#define K_   8192
#define QOFF 8388608   // float offset of indices in d_out
#define CAP  92
#define EPS  8e-4f
#define KSPLIT 4
#define KCHUNK (K_ / KSPLIT)      // 2048
#define PANEL  16
#define NPANEL (KCHUNK / PANEL)   // 128

// scratch layout inside d_out (byte offsets). Quantized region [0,33554432)
// holds all scratch; consumed before gather overwrites it. Index region
// [33554432, 33685504) is written only by rescore.
#define XBF_OFF   0u          // ushort[32768*256]  16MB  bf16(x) [n][c]
#define CBBF_OFF  16777216u   // ushort[8192*256]    4MB  bf16(cb) [k][c]
#define CAND_OFF  20971520u   // int[32768*92]   11.5MB  candidate lists
#define CNT_OFF   33030144u   // int[32768]
#define XSQ_OFF   33161216u   // float[32768]
#define CBSQ_OFF  33292288u   // float[8192]  (ends 33,325,056 < 33,554,432)

typedef __attribute__((ext_vector_type(8))) short bf16x8;
typedef __attribute__((ext_vector_type(4))) float f32x4;

__device__ inline void gload_lds16(const void* g, void* l) {
    __builtin_amdgcn_global_load_lds((const __attribute__((address_space(1))) void*)g,
                                     (__attribute__((address_space(3))) void*)l, 16, 0, 0);
}
__device__ inline unsigned short bfbits(float f) {
    __hip_bfloat16 h = __float2bfloat16(f);
    return *(unsigned short*)&h;
}

// ---------- prep_x: transpose x -> bf16 [n][c], xsq[n], cnt=0 ----------
__global__ __launch_bounds__(256) void prep_x(const float* __restrict__ x,
                                              char* __restrict__ outb) {
    __shared__ float xs[C_][66];
    unsigned short* xbf = (unsigned short*)(outb + XBF_OFF);
    float* xsq = (float*)(outb + XSQ_OFF);
    int*   cnt = (int*)(outb + CNT_OFF);
    const int t = threadIdx.x;
    const int n0 = blockIdx.x * 64;
    const int b = n0 >> 10, p0 = n0 & 1023;
    for (int i = 0; i < 64; ++i) {
        int f = t + 256 * i; int c = f >> 6, nl = f & 63;
        xs[c][nl] = x[(b * C_ + c) * P_ + p0 + nl];
    }
    __syncthreads();
    if (t < 64) {
        double acc = 0.0;
        for (int c = 0; c < C_; ++c) { float v = xs[c][t]; float pq = v * v; acc += (double)pq; }
        xsq[n0 + t] = (float)acc;
        cnt[n0 + t] = 0;
    }
    for (int i = 0; i < 64; ++i) {
        int f = t + 256 * i; int nl = f >> 8, c = f & 255;
        xbf[(n0 + nl) * C_ + c] = bfbits(xs[c][nl]);
    }
}

// ---------- prep_cb: cbsq (f32 squares, f64 sum, round once) + bf16 copy ----------
__global__ __launch_bounds__(256) void prep_cb(const float* __restrict__ cb,
                                               char* __restrict__ outb) {
    float* cbsq = (float*)(outb + CBSQ_OFF);
    unsigned short* cbbf = (unsigned short*)(outb + CBBF_OFF);
    const int row  = blockIdx.x * 4 + (threadIdx.x >> 6);
    const int lane = threadIdx.x & 63;
    const float4 v = *reinterpret_cast<const float4*>(cb + row * C_ + lane * 4);
    float p0 = v.x * v.x, p1 = v.y * v.y, p2 = v.z * v.z, p3 = v.w * v.w;
    double acc = (double)p0 + (double)p1 + (double)p2 + (double)p3;
    for (int off = 32; off; off >>= 1) acc += __shfl_down(acc, off, 64);
    if (lane == 0) cbsq[row] = (float)acc;
    ushort4 u = { bfbits(v.x), bfbits(v.y), bfbits(v.z), bfbits(v.w) };
    *reinterpret_cast<ushort4*>(cbbf + row * C_ + lane * 4) = u;
}

// ---------- vq_wave: barrier-free, wave-private double-buffered panels ----------
// grid 512 x 256thr. Block = 4 independent waves. Wave: 64 n (x-frags in 128
// VGPR), streams its chunk's cb in 16-k panels through its private 16KB LDS
// slice with counted s_waitcnt vmcnt(8). Zero __syncthreads in main loop.
__global__ __launch_bounds__(256, 2) void vq_wave(char* __restrict__ outb) {
    __shared__ unsigned short Bt[4][8192];  // 16KB per wave (2 x 8KB halves)
    __shared__ float csq_l[KCHUNK];         // 8KB block-shared
    const unsigned short* xbf  = (const unsigned short*)(outb + XBF_OFF);
    const unsigned short* cbbf = (const unsigned short*)(outb + CBBF_OFF);
    const float* cbsq = (const float*)(outb + CBSQ_OFF);
    int* cnt  = (int*)(outb + CNT_OFF);
    int* cand = (int*)(outb + CAND_OFF);

    const int t = threadIdx.x;
    const int l = t & 63, w = t >> 6;
    const int id = blockIdx.x;
    const int xcd = id & 7;
    const int chunk = xcd >> 1;                     // XCD pair -> chunk (L2-resident 1MB)
    const int nblk = (id >> 3) * 2 + (xcd & 1);     // bijective over [0,128)
    const int n0 = nblk * 256 + w * 64;
    const int k0c = chunk * KCHUNK;
    unsigned short* myB = &Bt[w][0];

    // --- setup: stage cbsq chunk (block-shared) ---
    #pragma unroll
    for (int i = 0; i < 2; ++i)
        gload_lds16(cbsq + k0c + (w * 2 + i) * 256 + l * 4,
                    (char*)csq_l + (w * 2 + i) * 1024);

    // --- setup: wave-local x frags (64 n x 256 c) via two 32-row stages ---
    bf16x8 bx[4][8];
    #pragma unroll
    for (int half = 0; half < 2; ++half) {
        #pragma unroll
        for (int s = 0; s < 16; ++s) {
            const int dr = 2 * s + (l >> 5);
            gload_lds16(xbf + (size_t)(n0 + half * 32 + dr) * C_ + (((l & 31) ^ (dr & 7)) * 8),
                        (char*)myB + s * 1024);
        }
        asm volatile("s_waitcnt vmcnt(0)" ::: "memory");
        __builtin_amdgcn_sched_barrier(0);
        #pragma unroll
        for (int jj = 0; jj < 2; ++jj) {
            const int j = half * 2 + jj;
            const int r = jj * 16 + (l & 15);
            #pragma unroll
            for (int kc = 0; kc < 8; ++kc) {
                const int gs = (kc * 4 + (l >> 4)) ^ (r & 7);
                bx[j][kc] = *reinterpret_cast<const bf16x8*>((const char*)myB + r * 512 + gs * 16);
            }
        }
        asm volatile("s_waitcnt lgkmcnt(0)" ::: "memory");
        __builtin_amdgcn_sched_barrier(0);
    }
    __syncthreads();                 // csq_l visible to all waves (setup only)

    // --- main loop: wave-private pipeline, counted vmcnt, no barriers ---
    auto stageP = [&](int p, int buf) {            // 8 gload_lds = 16 k-rows
        const unsigned short* src = cbbf + (size_t)(k0c + p * PANEL) * C_;
        #pragma unroll
        for (int s = 0; s < 8; ++s) {
            const int dr = 2 * s + (l >> 5);
            gload_lds16(src + (size_t)dr * C_ + (((l & 31) ^ (dr & 7)) * 8),
                        (char*)myB + buf * 8192 + s * 1024);
        }
    };

    stageP(0, 0);
    stageP(1, 1);
    float th[4] = {3e38f, 3e38f, 3e38f, 3e38f};

    for (int p = 0; p < NPANEL; ++p) {
        const int cur = p & 1;
        asm volatile("s_waitcnt vmcnt(8)" ::: "memory");   // panel p landed; p+1 in flight
        __builtin_amdgcn_sched_barrier(0);

        f32x4 acc[4];
        #pragma unroll
        for (int j = 0; j < 4; ++j) acc[j] = (f32x4)(0.f);
        const int r = l & 15;
        #pragma unroll
        for (int kc = 0; kc < 8; ++kc) {
            const int gs = (kc * 4 + (l >> 4)) ^ (r & 7);
            const bf16x8 ak = *reinterpret_cast<const bf16x8*>(
                (const char*)myB + cur * 8192 + r * 512 + gs * 16);
            #pragma unroll
            for (int j = 0; j < 4; ++j)
                acc[j] = __builtin_amdgcn_mfma_f32_16x16x32_bf16(ak, bx[j][kc], acc[j], 0, 0, 0);
        }
        const float4 cqv = *reinterpret_cast<const float4*>(csq_l + p * PANEL + (l >> 4) * 4);

        asm volatile("s_waitcnt lgkmcnt(0)" ::: "memory");  // LDS reads drained
        __builtin_amdgcn_sched_barrier(0);
        stageP((p + 2) & (NPANEL - 1), cur);                // prefetch p+2 (wraps harmlessly)

        // epilogue: D[row=k-local=(l>>4)*4+q][col=n-local=j*16+(l&15)]
        const float cq[4] = {cqv.x, cqv.y, cqv.z, cqv.w};
        #pragma unroll
        for (int j = 0; j < 4; ++j) {
            float s[4];
            #pragma unroll
            for (int q = 0; q < 4; ++q) s[q] = fmaf(-2.f, acc[j][q], cq[q]);
            float m = fminf(fminf(s[0], s[1]), fminf(s[2], s[3]));
            m = fminf(m, __shfl_xor(m, 16, 64));
            m = fminf(m, __shfl_xor(m, 32, 64));
            th[j] = fminf(th[j], m);                // includes current panel
            const float thE = th[j] + EPS;
            const int ng = n0 + j * 16 + (l & 15);
            #pragma unroll
            for (int q = 0; q < 4; ++q) {
                if (s[q] < thE) {
                    const int kg = k0c + p * PANEL + (l >> 4) * 4 + q;
                    const int pos = atomicAdd(&cnt[ng], 1);
                    if (pos < CAP) cand[ng * CAP + pos] = kg;
                }
            }
        }
    }
}

// ---------- rescore: exact f32 chain; full-scan fallback on overflow ----------
__global__ __launch_bounds__(256) void rescore(const float* __restrict__ x,
                                               const float* __restrict__ cb,
                                               float* __restrict__ outf,
                                               char* __restrict__ outb) {
    __shared__ float xs[C_ * 65];    // xs[c*65 + nl]: bank-clean both ways
    const float* cbsq = (const float*)(outb + CBSQ_OFF);
    const float* xsq  = (const float*)(outb + XSQ_OFF);
    const int*   cnt  = (const int*)(outb + CNT_OFF);
    const int*   cand = (const int*)(outb + CAND_OFF);
    const int t = threadIdx.x, l = t & 63, wv = t >> 6;
    const int nb = blockIdx.x * 64;
    const int b = nb >> 10, p0 = nb & 1023;
    for (int i = 0; i < 64; ++i) {
        int f = t + 256 * i; int c = f >> 6, nl = f & 63;
        xs[c * 65 + nl] = x[(b * C_ + c) * P_ + p0 + nl];
    }
    __syncthreads();

    for (int r = 0; r < 16; ++r) {
        const int row = wv * 16 + r;
        const int n = nb + row;
        const int m = cnt[n];
        const float xq = xsq[n];
        float xl[4];
        #pragma unroll
        for (int cc = 0; cc < 4; ++cc) xl[cc] = xs[(cc * 64 + l) * 65 + row];

        float s2 = 3e38f; int bk = 0x7FFFFFFF;
        auto score_one = [&](int k) {
            float part = 0.f;
            #pragma unroll
            for (int cc = 0; cc < 4; ++cc)
                part = fmaf(xl[cc], cb[(size_t)k * C_ + cc * 64 + l], part);
            #pragma unroll
            for (int off = 32; off; off >>= 1) part += __shfl_xor(part, off, 64);
            const float s1 = xq - 2.0f * part;   // accurate dot, ref f32 chain
            const float sck = s1 + cbsq[k];
            if (sck < s2 || (sck == s2 && k < bk)) { s2 = sck; bk = k; }
        };

        if (m == 0 || m > CAP) {
            for (int k = 0; k < K_; ++k) score_one(k);      // safe fallback
        } else {
            for (int cidx = 0; cidx < m; ++cidx)
                score_one(__builtin_amdgcn_readfirstlane(cand[n * CAP + cidx]));
        }
        if (l == 0) outf[QOFF + n] = (float)bk;
    }
}

// ---------- gather: quantized[b][c][p] = cb[idx[n]][c] ----------
__global__ __launch_bounds__(256) void gather(const float* __restrict__ cb,
                                              float* __restrict__ outf) {
    __shared__ int kf[64];
    const int t = threadIdx.x;
    const int n0 = blockIdx.x * 64;
    const int b = n0 >> 10, p0 = n0 & 1023;
    if (t < 64) kf[t] = (int)outf[QOFF + n0 + t];
    __syncthreads();
    for (int i = 0; i < 64; ++i) {
        int f = t + 256 * i; int c = f >> 6, nl = f & 63;
        outf[(b * C_ + c) * P_ + p0 + nl] = cb[kf[nl] * C_ + c];
    }
}

extern "C" void kernel_launch(void* const* d_in, const int* in_sizes, int n_in,
                              void* d_out, int out_size, void* d_ws, size_t ws_size,
                              hipStream_t stream) {
    const float* x  = (const float*)d_in[0];
    const float* cb = (const float*)d_in[1];
    float* outf = (float*)d_out;
    char*  outb = (char*)d_out;

    prep_x<<<N_ / 64, 256, 0, stream>>>(x, outb);
    prep_cb<<<K_ / 4, 256, 0, stream>>>(cb, outb);
    vq_wave<<<128 * KSPLIT, 256, 0, stream>>>(outb);
    rescore<<<N_ / 64, 256, 0, stream>>>(x, cb, outf, outb);
    gather<<<N_ / 64, 256, 0, stream>>>(cb, outf);
}

// Round 9
// 931.374 us; speedup vs baseline: 4.8185x; 4.8185x over previous
//
#include <hip/hip_runtime.h>
#include <hip/hip_bf16.h>

#define C_   256
#define P_   1024
#define N_   32768
#define K_   8192
#define QOFF 8388608   // float offset of indices in d_out
#define CAP  58
#define EPS  8e-4f
#define PANEL  16
#define NPANEL 128     // panels per 2048-k chunk (one chunk per wave)

// scratch in d_out (byte offsets): quantized region holds xbf/cbbf/cbsq;
// xsq lives in the INDEX region (read per-row, then overwritten by the index).
// INVARIANT: nothing writes the quantized region until gather, which runs
// as a SEPARATE kernel after vq_fused (scratch dead by then).
#define XBF_OFF   0u          // ushort[32768*256]  16MB  bf16(x) [n][c]
#define CBBF_OFF  16777216u   // ushort[8192*256]    4MB  bf16(cb) [k][c]
#define CBSQ_OFF  20971520u   // float[8192]

typedef __attribute__((ext_vector_type(8))) short bf16x8;
typedef __attribute__((ext_vector_type(4))) float f32x4;

__device__ inline void gload_lds16(const void* g, void* l) {
    __builtin_amdgcn_global_load_lds((const __attribute__((address_space(1))) void*)g,
                                     (__attribute__((address_space(3))) void*)l, 16, 0, 0);
}
__device__ inline unsigned short bfbits(float f) {
    __hip_bfloat16 h = __float2bfloat16(f);
    return *(unsigned short*)&h;
}
__device__ inline unsigned fkey(float f) {
    unsigned u = __float_as_uint(f);
    return (u & 0x80000000u) ? ~u : (u | 0x80000000u);
}
__device__ inline float funkey(unsigned k) {
    unsigned u = (k & 0x80000000u) ? (k ^ 0x80000000u) : ~k;
    return __uint_as_float(u);
}

// ---------- prep_x: transpose x -> bf16 [n][c]; xsq -> index region ----------
__global__ __launch_bounds__(256) void prep_x(const float* __restrict__ x,
                                              float* __restrict__ outf,
                                              char* __restrict__ outb) {
    __shared__ float xs[C_][66];
    unsigned short* xbf = (unsigned short*)(outb + XBF_OFF);
    const int t = threadIdx.x;
    const int n0 = blockIdx.x * 64;
    const int b = n0 >> 10, p0 = n0 & 1023;
    for (int i = 0; i < 64; ++i) {
        int f = t + 256 * i; int c = f >> 6, nl = f & 63;
        xs[c][nl] = x[(b * C_ + c) * P_ + p0 + nl];
    }
    __syncthreads();
    if (t < 64) {
        double acc = 0.0;
        for (int c = 0; c < C_; ++c) { float v = xs[c][t]; float pq = v * v; acc += (double)pq; }
        outf[QOFF + n0 + t] = (float)acc;     // xsq, overwritten later by index
    }
    for (int i = 0; i < 64; ++i) {
        int f = t + 256 * i; int nl = f >> 8, c = f & 255;
        xbf[(n0 + nl) * C_ + c] = bfbits(xs[c][nl]);
    }
}

// ---------- prep_cb: cbsq (f32 squares, f64 sum, round once) + bf16 copy ----------
__global__ __launch_bounds__(256) void prep_cb(const float* __restrict__ cb,
                                               char* __restrict__ outb) {
    float* cbsq = (float*)(outb + CBSQ_OFF);
    unsigned short* cbbf = (unsigned short*)(outb + CBBF_OFF);
    const int row  = blockIdx.x * 4 + (threadIdx.x >> 6);
    const int lane = threadIdx.x & 63;
    const float4 v = *reinterpret_cast<const float4*>(cb + row * C_ + lane * 4);
    float p0 = v.x * v.x, p1 = v.y * v.y, p2 = v.z * v.z, p3 = v.w * v.w;
    double acc = (double)p0 + (double)p1 + (double)p2 + (double)p3;
    for (int off = 32; off; off >>= 1) acc += __shfl_down(acc, off, 64);
    if (lane == 0) cbsq[row] = (float)acc;
    ushort4 u = { bfbits(v.x), bfbits(v.y), bfbits(v.z), bfbits(v.w) };
    *reinterpret_cast<ushort4*>(cbbf + row * C_ + lane * 4) = u;
}

// ---------- vq_fused: block owns 64 n; 4 waves split K 4-ways; shared LDS
// threshold; LDS cand lists; exact rescore -> index. NO quantized writes. ----------
__global__ __launch_bounds__(256, 2) void vq_fused(const float* __restrict__ x,
                                                   const float* __restrict__ cb,
                                                   float* __restrict__ outf,
                                                   char* __restrict__ outb) {
    __shared__ unsigned short Bt[4][8192];   // 16KB per wave (2 x 8KB dbuf)
    __shared__ unsigned lth[64];             // running row-min (fkey)
    __shared__ int cnt[64];
    __shared__ int candL[64 * CAP];          // 14.5KB
    const unsigned short* xbf  = (const unsigned short*)(outb + XBF_OFF);
    const unsigned short* cbbf = (const unsigned short*)(outb + CBBF_OFF);
    const float* cbsq = (const float*)(outb + CBSQ_OFF);

    const int t = threadIdx.x;
    const int l = t & 63, w = t >> 6;
    const int n0 = blockIdx.x * 64;
    const int b = n0 >> 10;
    const int k0c = w * (K_ / 4);            // wave's 2048-k chunk
    unsigned short* myB = &Bt[w][0];

    if (t < 64) { lth[t] = fkey(3.0e38f); cnt[t] = 0; }

    // --- wave-local x B-frags for the block's 64 rows (two 32-row stages) ---
    bf16x8 bx[4][8];
    #pragma unroll
    for (int half = 0; half < 2; ++half) {
        #pragma unroll
        for (int s = 0; s < 16; ++s) {
            const int dr = 2 * s + (l >> 5);
            gload_lds16(xbf + (size_t)(n0 + half * 32 + dr) * C_ + (((l & 31) ^ (dr & 7)) * 8),
                        (char*)myB + s * 1024);
        }
        asm volatile("s_waitcnt vmcnt(0)" ::: "memory");
        __builtin_amdgcn_sched_barrier(0);
        #pragma unroll
        for (int jj = 0; jj < 2; ++jj) {
            const int j = half * 2 + jj;
            const int r = jj * 16 + (l & 15);
            #pragma unroll
            for (int kc = 0; kc < 8; ++kc) {
                const int gs = (kc * 4 + (l >> 4)) ^ (r & 7);
                bx[j][kc] = *reinterpret_cast<const bf16x8*>((const char*)myB + r * 512 + gs * 16);
            }
        }
        asm volatile("s_waitcnt lgkmcnt(0)" ::: "memory");
        __builtin_amdgcn_sched_barrier(0);
    }
    __syncthreads();                         // lth/cnt init visible

    auto stageP = [&](int p, int half) {     // 16 k-rows = 8 gload_lds
        const unsigned short* src = cbbf + (size_t)(k0c + p * PANEL) * C_;
        #pragma unroll
        for (int s = 0; s < 8; ++s) {
            const int dr = 2 * s + (l >> 5);
            gload_lds16(src + (size_t)dr * C_ + (((l & 31) ^ (dr & 7)) * 8),
                        (char*)myB + half * 8192 + s * 1024);
        }
    };
    auto body = [&](int half, float4 cqv, int p) {
        f32x4 acc[4];
        #pragma unroll
        for (int j = 0; j < 4; ++j) acc[j] = (f32x4)(0.f);
        const int r = l & 15;
        #pragma unroll
        for (int kc = 0; kc < 8; ++kc) {
            const int gs = (kc * 4 + (l >> 4)) ^ (r & 7);
            const bf16x8 ak = *reinterpret_cast<const bf16x8*>(
                (const char*)myB + half * 8192 + r * 512 + gs * 16);
            #pragma unroll
            for (int j = 0; j < 4; ++j)
                acc[j] = __builtin_amdgcn_mfma_f32_16x16x32_bf16(ak, bx[j][kc], acc[j], 0, 0, 0);
        }
        const float cq[4] = {cqv.x, cqv.y, cqv.z, cqv.w};
        // scores; per-row panel-min -> shared running min (records argument:
        // true argmin is always within EPS of ANY valid running-min value)
        #pragma unroll
        for (int j = 0; j < 4; ++j) {
            #pragma unroll
            for (int q = 0; q < 4; ++q) acc[j][q] = fmaf(-2.f, acc[j][q], cq[q]);
            float m = fminf(fminf(acc[j][0], acc[j][1]), fminf(acc[j][2], acc[j][3]));
            m = fminf(m, __shfl_xor(m, 16, 64));
            m = fminf(m, __shfl_xor(m, 32, 64));
            if (l < 16) atomicMin(&lth[j * 16 + l], fkey(m));
        }
        #pragma unroll
        for (int j = 0; j < 4; ++j) {
            const int rloc = j * 16 + (l & 15);
            const float th = funkey(lth[rloc]) + EPS;
            #pragma unroll
            for (int q = 0; q < 4; ++q) {
                if (acc[j][q] < th) {
                    const int kg = k0c + p * PANEL + (l >> 4) * 4 + q;
                    const int pos = atomicAdd(&cnt[rloc], 1);
                    if (pos < CAP) candL[rloc * CAP + pos] = kg;
                }
            }
        }
    };
    auto csq = [&](int p) {
        return *reinterpret_cast<const float4*>(cbsq + k0c + p * PANEL + (l >> 4) * 4);
    };

    // --- wave-private pipeline: 9 VM loads/region, counted vmcnt, no barriers ---
    stageP(0, 0); float4 cqA = csq(0);
    stageP(1, 1); float4 cqB = csq(1);
    for (int pp = 0; pp < NPANEL; pp += 2) {
        asm volatile("s_waitcnt vmcnt(9)" ::: "memory");
        __builtin_amdgcn_sched_barrier(0);
        body(0, cqA, pp);
        asm volatile("s_waitcnt lgkmcnt(0)" ::: "memory");
        __builtin_amdgcn_sched_barrier(0);
        stageP((pp + 2) & (NPANEL - 1), 0); cqA = csq((pp + 2) & (NPANEL - 1));
        asm volatile("s_waitcnt vmcnt(9)" ::: "memory");
        __builtin_amdgcn_sched_barrier(0);
        body(1, cqB, pp + 1);
        asm volatile("s_waitcnt lgkmcnt(0)" ::: "memory");
        __builtin_amdgcn_sched_barrier(0);
        stageP((pp + 3) & (NPANEL - 1), 1); cqB = csq((pp + 3) & (NPANEL - 1));
    }
    __syncthreads();                         // all collects visible; vm drained

    // --- fused rescore: wave w handles rows w*16..w*16+15 ---
    for (int r = 0; r < 16; ++r) {
        const int rloc = w * 16 + r;
        const int n = n0 + rloc;
        const int ppos = n & 1023;
        const int m = cnt[rloc];
        const float xq = outf[QOFF + n];     // xsq (overwritten below)
        float s2 = 3e38f; int bk = 0x7FFFFFFF;

        if (m >= 1 && m <= CAP) {
            float xl[4];
            #pragma unroll
            for (int cc = 0; cc < 4; ++cc)
                xl[cc] = x[(size_t)(b * C_ + cc * 64 + l) * P_ + ppos];
            for (int base = 0; base < m; base += 4) {
                int ku[4]; float pt[4];
                #pragma unroll
                for (int u = 0; u < 4; ++u) {
                    int ci = base + u; if (ci > m - 1) ci = m - 1;
                    ku[u] = candL[rloc * CAP + ci];
                    float part = 0.f;
                    #pragma unroll
                    for (int cc = 0; cc < 4; ++cc)
                        part = fmaf(xl[cc], cb[(size_t)ku[u] * C_ + cc * 64 + l], part);
                    pt[u] = part;
                }
                #pragma unroll
                for (int off = 32; off; off >>= 1) {
                    #pragma unroll
                    for (int u = 0; u < 4; ++u) pt[u] += __shfl_xor(pt[u], off, 64);
                }
                #pragma unroll
                for (int u = 0; u < 4; ++u) {
                    if (base + u < m) {
                        const float sck = (xq - 2.0f * pt[u]) + cbsq[ku[u]];
                        if (sck < s2 || (sck == s2 && ku[u] < bk)) { s2 = sck; bk = ku[u]; }
                    }
                }
            }
        } else {
            // overflow fallback (P ~ 1e-6): lane-per-k exact scan, x row via LDS
            float* xls = (float*)&Bt[w][0];
            #pragma unroll
            for (int i = 0; i < 4; ++i)
                xls[l + 64 * i] = x[(size_t)(b * C_ + l + 64 * i) * P_ + ppos];
            asm volatile("s_waitcnt lgkmcnt(0)" ::: "memory");
            __builtin_amdgcn_sched_barrier(0);
            for (int kk = 0; kk < K_ / 64; ++kk) {
                const int k = 64 * kk + l;
                float acc = 0.f;
                #pragma unroll 8
                for (int c4 = 0; c4 < 64; ++c4) {
                    const float4 xv = *reinterpret_cast<const float4*>(&xls[c4 * 4]);
                    const float4 cv = *reinterpret_cast<const float4*>(&cb[(size_t)k * C_ + c4 * 4]);
                    acc = fmaf(xv.x, cv.x, acc); acc = fmaf(xv.y, cv.y, acc);
                    acc = fmaf(xv.z, cv.z, acc); acc = fmaf(xv.w, cv.w, acc);
                }
                const float sck = (xq - 2.0f * acc) + cbsq[k];
                if (sck < s2 || (sck == s2 && k < bk)) { s2 = sck; bk = k; }
            }
        }
        #pragma unroll
        for (int off = 32; off; off >>= 1) {
            const float so = __shfl_xor(s2, off, 64);
            const int   ko = __shfl_xor(bk, off, 64);
            if (so < s2 || (so == s2 && ko < bk)) { s2 = so; bk = ko; }
        }
        if (l == 0) outf[QOFF + n] = (float)bk;
    }
}

// ---------- gather (separate kernel, AFTER all scratch reads are done):
// quantized[b][c][p] = cb[idx[n]][c] ----------
__global__ __launch_bounds__(256) void gather(const float* __restrict__ cb,
                                              float* __restrict__ outf) {
    __shared__ int kf[64];
    const int t = threadIdx.x;
    const int n0 = blockIdx.x * 64;
    const int b = n0 >> 10, p0 = n0 & 1023;
    if (t < 64) kf[t] = (int)outf[QOFF + n0 + t];
    __syncthreads();
    for (int i = 0; i < 64; ++i) {
        int f = t + 256 * i; int c = f >> 6, nl = f & 63;
        outf[(b * C_ + c) * P_ + p0 + nl] = cb[(size_t)kf[nl] * C_ + c];
    }
}

extern "C" void kernel_launch(void* const* d_in, const int* in_sizes, int n_in,
                              void* d_out, int out_size, void* d_ws, size_t ws_size,
                              hipStream_t stream) {
    const float* x  = (const float*)d_in[0];
    const float* cb = (const float*)d_in[1];
    float* outf = (float*)d_out;
    char*  outb = (char*)d_out;

    prep_x<<<N_ / 64, 256, 0, stream>>>(x, outf, outb);
    prep_cb<<<K_ / 4, 256, 0, stream>>>(cb, outb);
    vq_fused<<<N_ / 64, 256, 0, stream>>>(x, cb, outf, outb);
    gather<<<N_ / 64, 256, 0, stream>>>(cb, outf);
}